// Round 5
// baseline (128.149 us; speedup 1.0000x reference)
//
#include <hip/hip_runtime.h>
#include <hip/hip_bf16.h>

// SAGAN self-attention, MI355X gfx950. B=4, C=64, H=W=128, N=16384, M=4096.
// fp32 in/out. Round 15: second occupancy doubling. R14 landed 47.4 µs with
// VALU-busy time 26.4 µs and 28% occupancy (grid 512 = 2 blocks/CU hard cap).
// Now grid 1024 (64 n/block), 8 waves = 2 n-subtiles x 4 m-quarters (1024 m
// each, 16 sts x 64 m). LDS still 40960 B -> 4 blocks/CU, launch_bounds
// (512,8) pins VGPR <= 64 for 8 waves/SIMD. 8-slot XOR swizzle (^(c&7));
// wave G-read tiles all 32 banks at the 8-words/bank minimum. Quarters 1-3
// dump acc (80B stride, bank-balanced) + l to retired staging LDS; quarter 0
// combines + epilogue. Inner tile = R13 verbatim (1 score MFMA + 2 PV MFMA
// per 32x32 tile, pi-permuted gG, VALU pk-add denominator).
// Layouts: 32x32x16 A[row=lane&31][k=8h+j], B[k=8h+j][col=lane&31]
// (h=lane>>5); C/D[row=(r&3)+8(r>>2)+4h][col=lane&31].

typedef __attribute__((ext_vector_type(16))) float f32x16;
typedef __attribute__((ext_vector_type(4))) float f32x4;
typedef __attribute__((ext_vector_type(2))) float f32x2;
typedef __attribute__((ext_vector_type(8))) short s16x8;

__device__ __forceinline__ unsigned short f32_bf16(float f) {
    unsigned int u = __float_as_uint(f);
    return (unsigned short)((u + 0x7fffu + ((u >> 16) & 1u)) >> 16);  // RNE
}
__device__ __forceinline__ unsigned int pk_bf16(float a, float b) {
    return (unsigned int)f32_bf16(a) | ((unsigned int)f32_bf16(b) << 16);
}
__device__ __forceinline__ unsigned int pk_rh(float a, float b) {   // round-half-up
    unsigned int au = __float_as_uint(a) + 0x8000u;
    unsigned int bu = __float_as_uint(b) + 0x8000u;
    return __builtin_amdgcn_perm(bu, au, 0x07060302u);
}
__device__ __forceinline__ unsigned int pk_tr(float a, float b) {   // truncate
    return __builtin_amdgcn_perm(__float_as_uint(b), __float_as_uint(a), 0x07060302u);
}
// async 16B/lane global->LDS DMA; lds dest = wave-uniform base + lane*16
__device__ __forceinline__ void async16(const void* g, void* l) {
    __builtin_amdgcn_global_load_lds(
        (const __attribute__((address_space(1))) unsigned int*)g,
        (__attribute__((address_space(3))) unsigned int*)l, 16, 0, 0);
}

// ---------------- proj: theta/phi/g 1x1 conv + 2x2 maxpool, MFMA ----------------
// (round 13 verbatim — passed; emits pi-permuted gG for the 32x32 PV)
__global__ __launch_bounds__(256) void proj_kernel(
    const float* __restrict__ x,
    const float* __restrict__ w_theta, const float* __restrict__ w_phi,
    const float* __restrict__ w_g,
    __hip_bfloat16* __restrict__ thG,   // [b][n][8]  (theta * log2e)
    __hip_bfloat16* __restrict__ phG,   // [b][m][8]
    __hip_bfloat16* __restrict__ gG)    // [b][32][4096], pi-permuted per 32-m chunk
{
    __shared__ __align__(16) unsigned short x_s[128 * 72];  // [pix][c], 144 B rows
    int tid = threadIdx.x;
    int bx = blockIdx.x;
    int b = bx >> 7, mh = (bx >> 1) & 63, ph = bx & 1;

    {   // phase 1: float4 loads (c-pair per thread), packed u32 LDS transpose
        int cp = tid >> 3, s = tid & 7;
        const float* xb = x + ((size_t)b << 20) + (size_t)(2 * mh) * 128 + 64 * ph;
        const float* p0r = xb + ((size_t)(2 * cp) << 14);
        const float* p1r = p0r + (1 << 14);
#pragma unroll
        for (int py = 0; py < 2; py++)
#pragma unroll
            for (int t = 0; t < 2; t++) {
                int pxl = 4 * s + 32 * t;
                float4 a = *(const float4*)(p0r + py * 128 + pxl);
                float4 c = *(const float4*)(p1r + py * 128 + pxl);
                int pix = py * 64 + pxl;
                *(unsigned int*)&x_s[(pix + 0) * 72 + 2 * cp] = pk_rh(a.x, c.x);
                *(unsigned int*)&x_s[(pix + 1) * 72 + 2 * cp] = pk_rh(a.y, c.y);
                *(unsigned int*)&x_s[(pix + 2) * 72 + 2 * cp] = pk_rh(a.z, c.z);
                *(unsigned int*)&x_s[(pix + 3) * 72 + 2 * cp] = pk_rh(a.w, c.w);
            }
    }

    int lane = tid & 63, w = tid >> 6;
    int q = lane >> 4, nl = lane & 15;

    s16x8 A[3][2];
#pragma unroll
    for (int CT = 0; CT < 3; CT++) {
        const float* wsrc;
        float scale = 1.0f;
        if (CT == 0) {
            if (nl < 8) { wsrc = w_theta + nl * 64; scale = 1.44269504f; }
            else        { wsrc = w_phi + (nl - 8) * 64; }
        } else if (CT == 1) wsrc = w_g + nl * 64;
        else                wsrc = w_g + (16 + nl) * 64;
#pragma unroll
        for (int ks = 0; ks < 2; ks++) {
            const float4* p4 = (const float4*)(wsrc + 32 * ks + 8 * q);
            float4 a0 = p4[0], a1 = p4[1];
            s16x8 f;
            f[0] = (short)f32_bf16(a0.x * scale); f[1] = (short)f32_bf16(a0.y * scale);
            f[2] = (short)f32_bf16(a0.z * scale); f[3] = (short)f32_bf16(a0.w * scale);
            f[4] = (short)f32_bf16(a1.x * scale); f[5] = (short)f32_bf16(a1.y * scale);
            f[6] = (short)f32_bf16(a1.z * scale); f[7] = (short)f32_bf16(a1.w * scale);
            A[CT][ks] = f;
        }
    }
    __syncthreads();

    f32x4 acc[3][2];
#pragma unroll
    for (int ti = 0; ti < 2; ti++) {
        int tile = w + 4 * ti;
        const unsigned short* rb = x_s + (16 * tile + nl) * 72;
        s16x8 B0 = *(const s16x8*)(rb + 8 * q);
        s16x8 B1 = *(const s16x8*)(rb + 32 + 8 * q);
#pragma unroll
        for (int CT = 0; CT < 3; CT++) {
            f32x4 d = (f32x4){0.f, 0.f, 0.f, 0.f};
            d = __builtin_amdgcn_mfma_f32_16x16x32_bf16(A[CT][0], B0, d, 0, 0, 0);
            d = __builtin_amdgcn_mfma_f32_16x16x32_bf16(A[CT][1], B1, d, 0, 0, 0);
            acc[CT][ti] = d;
        }
    }

    if (q < 2) {
        unsigned short* thb = (unsigned short*)thG + ((size_t)b << 14) * 8;
#pragma unroll
        for (int ti = 0; ti < 2; ti++) {
            int n = (2 * mh + ti) * 128 + 64 * ph + 16 * w + nl;
            uint2 tv;
            tv.x = pk_bf16(acc[0][ti][0], acc[0][ti][1]);
            tv.y = pk_bf16(acc[0][ti][2], acc[0][ti][3]);
            *(uint2*)(thb + (size_t)n * 8 + 4 * q) = tv;
        }
    }

    float pool[3][4];
#pragma unroll
    for (int CT = 0; CT < 3; CT++)
#pragma unroll
        for (int r = 0; r < 4; r++) {
            float a = fmaxf(acc[CT][0][r], acc[CT][1][r]);
            pool[CT][r] = fmaxf(a, __shfl_xor(a, 1));
        }

    int mm = 8 * w + (nl >> 1);
    int mbase = mh * 64 + ph * 32;
    if ((nl & 1) == 0) {
        if (q >= 2) {
            uint2 pv;
            pv.x = pk_bf16(pool[0][0], pool[0][1]);
            pv.y = pk_bf16(pool[0][2], pool[0][3]);
            *(uint2*)((unsigned short*)phG + ((size_t)(b * 4096 + mbase + mm)) * 8 + (q - 2) * 4) = pv;
        }
        // pi for 32x32 PV A-frags: i = 16*((mm>>4)&1) + 8*((mm>>2)&1) + 4*((mm>>3)&1) + (mm&3)
        int p = 16 * ((mm >> 4) & 1) + 8 * ((mm >> 2) & 1) + 4 * ((mm >> 3) & 1) + (mm & 3);
        int mstore = mbase + p;
#pragma unroll
        for (int CT = 1; CT < 3; CT++)
#pragma unroll
            for (int r = 0; r < 4; r++) {
                int cg = 16 * (CT - 1) + 4 * q + r;
                ((unsigned short*)gG)[((size_t)(b * 32 + cg) << 12) + mstore] =
                    f32_bf16(pool[CT][r]);
            }
    }
}

// ---------------- attn: m-quarter 8-wave, 32x32x16 score -> exp2 -> 2x PV ------
// Grid 1024 = b(4) x n-tile(256). Block 512 thr = 2 n-subtiles x 4 m-quarters.
// Each quarter: 16 sts x 64 m. LDS per quarter: g dbuf 2x4096 + phi dbuf 2x1024.
// Map: g [0,32768) = buf*16384 + hf*4096; phi [32768,40960) = buf*4096 + hf*1024.
__global__ __launch_bounds__(512, 8) void attn_kernel(
    const __hip_bfloat16* __restrict__ thG, const __hip_bfloat16* __restrict__ phG,
    const __hip_bfloat16* __restrict__ gG,
    const float* __restrict__ w_o, const float* __restrict__ gamma,
    const float* __restrict__ x, float* __restrict__ out)
{
    __shared__ __align__(64) unsigned char smem[40960];

    int tid = threadIdx.x, lane = tid & 63, w = tid >> 6;   // w: 0..7
    int ns = w & 1, hf = w >> 1;     // ns: n-subtile, hf: m-quarter (0..3)
    int q = lane >> 4, nl = lane & 15;
    int c31 = lane & 31, h = lane >> 5;
    int bx = blockIdx.x;
    int b  = bx >> 8;
    int n0 = (bx & 255) << 6;
    int nw = n0 + ns * 32;

    const unsigned short* thb = (const unsigned short*)thG + ((size_t)b << 14) * 8;
    const unsigned short* phb = (const unsigned short*)phG + ((size_t)b << 12) * 8;
    const unsigned short* ggb = (const unsigned short*)gG + ((size_t)b << 17);

    // theta B-frag (32x32x16): B[k=c=8h+j][col=n=c31]; h=1/j=0 = bias slot
    s16x8 BT = (s16x8){0, 0, 0, 0, 0, 0, 0, 0};
    if (h == 0) BT = *(const s16x8*)(thb + (size_t)(nw + c31) * 8);
    else        BT[0] = (short)0xC167;   // bf16(-14.4375)
    // phi A-frag const part: h=1/j=0 -> k=8 slot = 1.0
    s16x8 Fc = (s16x8){0, 0, 0, 0, 0, 0, 0, 0};
    if (h == 1) Fc[0] = (short)0x3F80;

    f32x16 acc = {};          // PV acc: [row=c=(r&3)+8(r>>2)+4h][col=n=c31]
    f32x2  l2 = (f32x2){0.f, 0.f};

    // staging: each quarter stages all 32 g-rows x its 64-m window per st.
    // Wave (hf,ns): 2 g-calls (rows 16ns..+7, 16ns+8..+15); ns==0 also phi.
    // 8 slots/row (16B = 8 m); LDS slot s of row r holds logical slot s^(r&7).
    int rA = 16 * ns + (lane >> 3);
    int rB = rA + 8;
    int wq = hf << 10;                   // quarter m-base (elements)
    const unsigned short* gsrcA = ggb + ((size_t)rA << 12) + wq
                                  + (((lane & 7) ^ (rA & 7)) << 3);
    const unsigned short* gsrcB = ggb + ((size_t)rB << 12) + wq
                                  + (((lane & 7) ^ (rB & 7)) << 3);
    const unsigned short* psrc  = phb + (size_t)(wq + lane) * 8;
    unsigned char* gdstA = smem + hf * 4096 + ns * 2048;     // + buf*16384
    unsigned char* gdstB = gdstA + 1024;
    unsigned char* pdst  = smem + 32768 + hf * 1024;         // + buf*4096 (ns==0)

    // pre-stage st 0 -> buf 0
    async16(gsrcA, gdstA);
    async16(gsrcB, gdstB);
    if (ns == 0) async16(psrc, pdst);
    __syncthreads();

    for (int st = 0; st < 16; st++) {
        const unsigned char* gcur = smem + (st & 1) * 16384 + hf * 4096;
        const unsigned char* pcur = smem + 32768 + (st & 1) * 4096 + hf * 1024;
        if (st < 15) {   // issue next st's DMA into the other buffers (no wait)
            int nb = (st + 1) & 1;
            int mo = (st + 1) << 6;          // 64 m-elements per st
            async16(gsrcA + mo, gdstA + nb * 16384);
            async16(gsrcB + mo, gdstB + nb * 16384);
            if (ns == 0) async16(psrc + (size_t)mo * 8, pdst + nb * 4096);
        }
#pragma unroll
        for (int t8 = 0; t8 < 2; t8++) {
            // phi A-frag: rows t8*32..+31 of this st window (contiguous 16B)
            s16x8 F = Fc;
            if (h == 0) F = *(const s16x8*)(pcur + ((t8 << 5) + c31) * 16);
            // G A-frags: logical slot 4*t8+2*pv+h, LDS slot = logical^(c31&7)
            int s0 = (t8 << 2) + h;
            int m7 = c31 & 7;
            s16x8 G1 = *(const s16x8*)(gcur + c31 * 128 + (((s0 + 0) ^ m7) << 4));
            s16x8 G2 = *(const s16x8*)(gcur + c31 * 128 + (((s0 + 2) ^ m7) << 4));

            f32x16 z = {};
            f32x16 S = __builtin_amdgcn_mfma_f32_32x32x16_bf16(F, BT, z, 0, 0, 0);

            float p0  = __builtin_amdgcn_exp2f(S[0]);
            float p1  = __builtin_amdgcn_exp2f(S[1]);
            float p2  = __builtin_amdgcn_exp2f(S[2]);
            float p3  = __builtin_amdgcn_exp2f(S[3]);
            float p4  = __builtin_amdgcn_exp2f(S[4]);
            float p5  = __builtin_amdgcn_exp2f(S[5]);
            float p6  = __builtin_amdgcn_exp2f(S[6]);
            float p7  = __builtin_amdgcn_exp2f(S[7]);
            float p8  = __builtin_amdgcn_exp2f(S[8]);
            float p9  = __builtin_amdgcn_exp2f(S[9]);
            float p10 = __builtin_amdgcn_exp2f(S[10]);
            float p11 = __builtin_amdgcn_exp2f(S[11]);
            float p12 = __builtin_amdgcn_exp2f(S[12]);
            float p13 = __builtin_amdgcn_exp2f(S[13]);
            float p14 = __builtin_amdgcn_exp2f(S[14]);
            float p15 = __builtin_amdgcn_exp2f(S[15]);

            // denominator on VALU: packed-f32 add tree (7 pk-adds)
            f32x2 u0 = (f32x2){p0, p1} + (f32x2){p2, p3};
            f32x2 u1 = (f32x2){p4, p5} + (f32x2){p6, p7};
            f32x2 u2 = (f32x2){p8, p9} + (f32x2){p10, p11};
            f32x2 u3 = (f32x2){p12, p13} + (f32x2){p14, p15};
            l2 += (u0 + u1) + (u2 + u3);

            // B-frags: direct in-lane packs (pi makes k-order = reg-order)
            uint4 ub1 = make_uint4(pk_tr(p0, p1), pk_tr(p2, p3),
                                   pk_tr(p4, p5), pk_tr(p6, p7));
            uint4 ub2 = make_uint4(pk_tr(p8, p9), pk_tr(p10, p11),
                                   pk_tr(p12, p13), pk_tr(p14, p15));
            s16x8 B1 = *(s16x8*)&ub1;
            s16x8 B2 = *(s16x8*)&ub2;

            acc = __builtin_amdgcn_mfma_f32_32x32x16_bf16(G1, B1, acc, 0, 0, 0);
            acc = __builtin_amdgcn_mfma_f32_32x32x16_bf16(G2, B2, acc, 0, 0, 0);
        }
        __syncthreads();   // single barrier/st; drains next-st DMA (vmcnt) too
    }

    // per-quarter denominator: combine h-halves (h=0: m%8<4, h=1: rest)
    float l = l2[0] + l2[1];
    l += __shfl_xor(l, 32);

    // cross-quarter combine: quarters 1..3 dump partials into retired LDS.
    // acc at 80B stride (bank-balanced), l as scalars.
    if (hf != 0) {
        int reg = (hf - 1) * 2 + ns;                       // 0..5
        *(f32x16*)(smem + reg * 5120 + lane * 80) = acc;   // [0, 30720)
        *(float*)(smem + 30720 + reg * 256 + lane * 4) = l;  // [30720, 32256)
    }
    __syncthreads();
    if (hf == 0) {
#pragma unroll
        for (int k = 0; k < 3; k++) {
            int reg = k * 2 + ns;
            acc += *(const f32x16*)(smem + reg * 5120 + lane * 80);
            l += *(const float*)(smem + 30720 + reg * 256 + lane * 4);
        }
        float linv = 1.0f / l;
        acc *= linv;

        // w_o A-frags: A[row=cc=16g4+nl][k=c=8q+j]
        s16x8 WO[4];
#pragma unroll
        for (int g4 = 0; g4 < 4; g4++) {
            const float4* wr = (const float4*)(w_o + (size_t)(g4 * 16 + nl) * 32 + q * 8);
            float4 a0 = wr[0], a1 = wr[1];
            WO[g4][0] = (short)f32_bf16(a0.x); WO[g4][1] = (short)f32_bf16(a0.y);
            WO[g4][2] = (short)f32_bf16(a0.z); WO[g4][3] = (short)f32_bf16(a0.w);
            WO[g4][4] = (short)f32_bf16(a1.x); WO[g4][5] = (short)f32_bf16(a1.y);
            WO[g4][6] = (short)f32_bf16(a1.z); WO[g4][7] = (short)f32_bf16(a1.w);
        }
        float gam = gamma[0];

        // O_s overlay [64 rows][80 B] at 34816 (no overlap with dump regions)
        unsigned char* O_s = smem + 34816;
        int nloc = ns * 32 + c31;
#pragma unroll
        for (int g2 = 0; g2 < 4; g2++) {
            uint2 ov;
            ov.x = pk_bf16(acc[4 * g2 + 0], acc[4 * g2 + 1]);
            ov.y = pk_bf16(acc[4 * g2 + 2], acc[4 * g2 + 3]);
            *(uint2*)(O_s + nloc * 80 + 16 * g2 + 8 * h) = ov;
        }
        int nloc0 = ns * 32 + nl;
        int nloc1 = nloc0 + 16;
        s16x8 OB0 = *(const s16x8*)(O_s + nloc0 * 80 + q * 16);  // wave-local rows
        s16x8 OB1 = *(const s16x8*)(O_s + nloc1 * 80 + q * 16);
#pragma unroll
        for (int g4 = 0; g4 < 4; g4++) {
            f32x4 e0 = (f32x4){0.f, 0.f, 0.f, 0.f};
            f32x4 e1 = (f32x4){0.f, 0.f, 0.f, 0.f};
            e0 = __builtin_amdgcn_mfma_f32_16x16x32_bf16(WO[g4], OB0, e0, 0, 0, 0);
            e1 = __builtin_amdgcn_mfma_f32_16x16x32_bf16(WO[g4], OB1, e1, 0, 0, 0);
#pragma unroll
            for (int r = 0; r < 4; r++) {
                int cc = g4 * 16 + q * 4 + r;
                size_t gi0 = (((size_t)(b * 64 + cc)) << 14) + nw + nl;
                out[gi0] = gam * e0[r] + x[gi0];
                size_t gi1 = gi0 + 16;
                out[gi1] = gam * e1[r] + x[gi1];
            }
        }
    }
}

extern "C" void kernel_launch(void* const* d_in, const int* in_sizes, int n_in,
                              void* d_out, int out_size, void* d_ws, size_t ws_size,
                              hipStream_t stream) {
    const float* x       = (const float*)d_in[0];
    const float* w_theta = (const float*)d_in[1];
    const float* w_phi   = (const float*)d_in[2];
    const float* w_g     = (const float*)d_in[3];
    const float* w_o     = (const float*)d_in[4];
    const float* gamma   = (const float*)d_in[5];
    float* out = (float*)d_out;

    __hip_bfloat16* thG = (__hip_bfloat16*)d_ws;        // 4*16384*8 = 1 MB
    __hip_bfloat16* phG = thG + 524288;                 // 4*4096*8  = 256 KB
    __hip_bfloat16* gG  = phG + 131072;                 // 4*32*4096 = 1 MB

    proj_kernel<<<512, 256, 0, stream>>>(x, w_theta, w_phi, w_g, thG, phG, gG);
    attn_kernel<<<1024, 512, 0, stream>>>(thG, phG, gG, w_o, gamma, x, out);
}

// Round 6
// 120.740 us; speedup vs baseline: 1.0614x; 1.0614x over previous
//
#include <hip/hip_runtime.h>
#include <hip/hip_bf16.h>

// SAGAN self-attention, MI355X gfx950. B=4, C=64, H=W=128, N=16384, M=4096.
// fp32 in/out. Round 16: fix the R15 spill regression. R15's launch_bounds
// (512,8) forced VGPR=32 -> scratch spills (WRITE_SIZE +22.5 MB, conflicts
// 2.1M, attn 54 µs). Same m-quarter structure (grid 1024, 8 waves = 2 n-sub x
// 4 m-quarters, 16 sts x 64 m, 40960 B LDS) but launch_bounds(512,6):
// VGPR cap ~85 fits the ~80 live regs spill-free, 6 waves/SIMD = 3 blocks/CU
// (24 waves/CU vs R14's 16). Inner tile = R13 verbatim (1 score MFMA + 2 PV
// MFMA per 32x32 tile, pi-permuted gG, VALU pk-add denominator).
// Layouts: 32x32x16 A[row=lane&31][k=8h+j], B[k=8h+j][col=lane&31]
// (h=lane>>5); C/D[row=(r&3)+8(r>>2)+4h][col=lane&31].

typedef __attribute__((ext_vector_type(16))) float f32x16;
typedef __attribute__((ext_vector_type(4))) float f32x4;
typedef __attribute__((ext_vector_type(2))) float f32x2;
typedef __attribute__((ext_vector_type(8))) short s16x8;

__device__ __forceinline__ unsigned short f32_bf16(float f) {
    unsigned int u = __float_as_uint(f);
    return (unsigned short)((u + 0x7fffu + ((u >> 16) & 1u)) >> 16);  // RNE
}
__device__ __forceinline__ unsigned int pk_bf16(float a, float b) {
    return (unsigned int)f32_bf16(a) | ((unsigned int)f32_bf16(b) << 16);
}
__device__ __forceinline__ unsigned int pk_rh(float a, float b) {   // round-half-up
    unsigned int au = __float_as_uint(a) + 0x8000u;
    unsigned int bu = __float_as_uint(b) + 0x8000u;
    return __builtin_amdgcn_perm(bu, au, 0x07060302u);
}
__device__ __forceinline__ unsigned int pk_tr(float a, float b) {   // truncate
    return __builtin_amdgcn_perm(__float_as_uint(b), __float_as_uint(a), 0x07060302u);
}
// async 16B/lane global->LDS DMA; lds dest = wave-uniform base + lane*16
__device__ __forceinline__ void async16(const void* g, void* l) {
    __builtin_amdgcn_global_load_lds(
        (const __attribute__((address_space(1))) unsigned int*)g,
        (__attribute__((address_space(3))) unsigned int*)l, 16, 0, 0);
}

// ---------------- proj: theta/phi/g 1x1 conv + 2x2 maxpool, MFMA ----------------
// (round 13 verbatim — passed; emits pi-permuted gG for the 32x32 PV)
__global__ __launch_bounds__(256) void proj_kernel(
    const float* __restrict__ x,
    const float* __restrict__ w_theta, const float* __restrict__ w_phi,
    const float* __restrict__ w_g,
    __hip_bfloat16* __restrict__ thG,   // [b][n][8]  (theta * log2e)
    __hip_bfloat16* __restrict__ phG,   // [b][m][8]
    __hip_bfloat16* __restrict__ gG)    // [b][32][4096], pi-permuted per 32-m chunk
{
    __shared__ __align__(16) unsigned short x_s[128 * 72];  // [pix][c], 144 B rows
    int tid = threadIdx.x;
    int bx = blockIdx.x;
    int b = bx >> 7, mh = (bx >> 1) & 63, ph = bx & 1;

    {   // phase 1: float4 loads (c-pair per thread), packed u32 LDS transpose
        int cp = tid >> 3, s = tid & 7;
        const float* xb = x + ((size_t)b << 20) + (size_t)(2 * mh) * 128 + 64 * ph;
        const float* p0r = xb + ((size_t)(2 * cp) << 14);
        const float* p1r = p0r + (1 << 14);
#pragma unroll
        for (int py = 0; py < 2; py++)
#pragma unroll
            for (int t = 0; t < 2; t++) {
                int pxl = 4 * s + 32 * t;
                float4 a = *(const float4*)(p0r + py * 128 + pxl);
                float4 c = *(const float4*)(p1r + py * 128 + pxl);
                int pix = py * 64 + pxl;
                *(unsigned int*)&x_s[(pix + 0) * 72 + 2 * cp] = pk_rh(a.x, c.x);
                *(unsigned int*)&x_s[(pix + 1) * 72 + 2 * cp] = pk_rh(a.y, c.y);
                *(unsigned int*)&x_s[(pix + 2) * 72 + 2 * cp] = pk_rh(a.z, c.z);
                *(unsigned int*)&x_s[(pix + 3) * 72 + 2 * cp] = pk_rh(a.w, c.w);
            }
    }

    int lane = tid & 63, w = tid >> 6;
    int q = lane >> 4, nl = lane & 15;

    s16x8 A[3][2];
#pragma unroll
    for (int CT = 0; CT < 3; CT++) {
        const float* wsrc;
        float scale = 1.0f;
        if (CT == 0) {
            if (nl < 8) { wsrc = w_theta + nl * 64; scale = 1.44269504f; }
            else        { wsrc = w_phi + (nl - 8) * 64; }
        } else if (CT == 1) wsrc = w_g + nl * 64;
        else                wsrc = w_g + (16 + nl) * 64;
#pragma unroll
        for (int ks = 0; ks < 2; ks++) {
            const float4* p4 = (const float4*)(wsrc + 32 * ks + 8 * q);
            float4 a0 = p4[0], a1 = p4[1];
            s16x8 f;
            f[0] = (short)f32_bf16(a0.x * scale); f[1] = (short)f32_bf16(a0.y * scale);
            f[2] = (short)f32_bf16(a0.z * scale); f[3] = (short)f32_bf16(a0.w * scale);
            f[4] = (short)f32_bf16(a1.x * scale); f[5] = (short)f32_bf16(a1.y * scale);
            f[6] = (short)f32_bf16(a1.z * scale); f[7] = (short)f32_bf16(a1.w * scale);
            A[CT][ks] = f;
        }
    }
    __syncthreads();

    f32x4 acc[3][2];
#pragma unroll
    for (int ti = 0; ti < 2; ti++) {
        int tile = w + 4 * ti;
        const unsigned short* rb = x_s + (16 * tile + nl) * 72;
        s16x8 B0 = *(const s16x8*)(rb + 8 * q);
        s16x8 B1 = *(const s16x8*)(rb + 32 + 8 * q);
#pragma unroll
        for (int CT = 0; CT < 3; CT++) {
            f32x4 d = (f32x4){0.f, 0.f, 0.f, 0.f};
            d = __builtin_amdgcn_mfma_f32_16x16x32_bf16(A[CT][0], B0, d, 0, 0, 0);
            d = __builtin_amdgcn_mfma_f32_16x16x32_bf16(A[CT][1], B1, d, 0, 0, 0);
            acc[CT][ti] = d;
        }
    }

    if (q < 2) {
        unsigned short* thb = (unsigned short*)thG + ((size_t)b << 14) * 8;
#pragma unroll
        for (int ti = 0; ti < 2; ti++) {
            int n = (2 * mh + ti) * 128 + 64 * ph + 16 * w + nl;
            uint2 tv;
            tv.x = pk_bf16(acc[0][ti][0], acc[0][ti][1]);
            tv.y = pk_bf16(acc[0][ti][2], acc[0][ti][3]);
            *(uint2*)(thb + (size_t)n * 8 + 4 * q) = tv;
        }
    }

    float pool[3][4];
#pragma unroll
    for (int CT = 0; CT < 3; CT++)
#pragma unroll
        for (int r = 0; r < 4; r++) {
            float a = fmaxf(acc[CT][0][r], acc[CT][1][r]);
            pool[CT][r] = fmaxf(a, __shfl_xor(a, 1));
        }

    int mm = 8 * w + (nl >> 1);
    int mbase = mh * 64 + ph * 32;
    if ((nl & 1) == 0) {
        if (q >= 2) {
            uint2 pv;
            pv.x = pk_bf16(pool[0][0], pool[0][1]);
            pv.y = pk_bf16(pool[0][2], pool[0][3]);
            *(uint2*)((unsigned short*)phG + ((size_t)(b * 4096 + mbase + mm)) * 8 + (q - 2) * 4) = pv;
        }
        // pi for 32x32 PV A-frags: i = 16*((mm>>4)&1) + 8*((mm>>2)&1) + 4*((mm>>3)&1) + (mm&3)
        int p = 16 * ((mm >> 4) & 1) + 8 * ((mm >> 2) & 1) + 4 * ((mm >> 3) & 1) + (mm & 3);
        int mstore = mbase + p;
#pragma unroll
        for (int CT = 1; CT < 3; CT++)
#pragma unroll
            for (int r = 0; r < 4; r++) {
                int cg = 16 * (CT - 1) + 4 * q + r;
                ((unsigned short*)gG)[((size_t)(b * 32 + cg) << 12) + mstore] =
                    f32_bf16(pool[CT][r]);
            }
    }
}

// ---------------- attn: m-quarter 8-wave, 32x32x16 score -> exp2 -> 2x PV ------
// Grid 1024 = b(4) x n-tile(256). Block 512 thr = 2 n-subtiles x 4 m-quarters.
// Each quarter: 16 sts x 64 m. LDS per quarter: g dbuf 2x4096 + phi dbuf 2x1024.
// Map: g [0,32768) = buf*16384 + hf*4096; phi [32768,40960) = buf*4096 + hf*1024.
__global__ __launch_bounds__(512, 6) void attn_kernel(
    const __hip_bfloat16* __restrict__ thG, const __hip_bfloat16* __restrict__ phG,
    const __hip_bfloat16* __restrict__ gG,
    const float* __restrict__ w_o, const float* __restrict__ gamma,
    const float* __restrict__ x, float* __restrict__ out)
{
    __shared__ __align__(64) unsigned char smem[40960];

    int tid = threadIdx.x, lane = tid & 63, w = tid >> 6;   // w: 0..7
    int ns = w & 1, hf = w >> 1;     // ns: n-subtile, hf: m-quarter (0..3)
    int q = lane >> 4, nl = lane & 15;
    int c31 = lane & 31, h = lane >> 5;
    int bx = blockIdx.x;
    int b  = bx >> 8;
    int n0 = (bx & 255) << 6;
    int nw = n0 + ns * 32;

    const unsigned short* thb = (const unsigned short*)thG + ((size_t)b << 14) * 8;
    const unsigned short* phb = (const unsigned short*)phG + ((size_t)b << 12) * 8;
    const unsigned short* ggb = (const unsigned short*)gG + ((size_t)b << 17);

    // theta B-frag (32x32x16): B[k=c=8h+j][col=n=c31]; h=1/j=0 = bias slot
    s16x8 BT = (s16x8){0, 0, 0, 0, 0, 0, 0, 0};
    if (h == 0) BT = *(const s16x8*)(thb + (size_t)(nw + c31) * 8);
    else        BT[0] = (short)0xC167;   // bf16(-14.4375)
    // phi A-frag const part: h=1/j=0 -> k=8 slot = 1.0
    s16x8 Fc = (s16x8){0, 0, 0, 0, 0, 0, 0, 0};
    if (h == 1) Fc[0] = (short)0x3F80;

    f32x16 acc = {};          // PV acc: [row=c=(r&3)+8(r>>2)+4h][col=n=c31]
    f32x2  l2 = (f32x2){0.f, 0.f};

    // staging: each quarter stages all 32 g-rows x its 64-m window per st.
    // Wave (hf,ns): 2 g-calls (rows 16ns..+7, 16ns+8..+15); ns==0 also phi.
    // 8 slots/row (16B = 8 m); LDS slot s of row r holds logical slot s^(r&7).
    int rA = 16 * ns + (lane >> 3);
    int rB = rA + 8;
    int wq = hf << 10;                   // quarter m-base (elements)
    const unsigned short* gsrcA = ggb + ((size_t)rA << 12) + wq
                                  + (((lane & 7) ^ (rA & 7)) << 3);
    const unsigned short* gsrcB = ggb + ((size_t)rB << 12) + wq
                                  + (((lane & 7) ^ (rB & 7)) << 3);
    const unsigned short* psrc  = phb + (size_t)(wq + lane) * 8;
    unsigned char* gdstA = smem + hf * 4096 + ns * 2048;     // + buf*16384
    unsigned char* gdstB = gdstA + 1024;
    unsigned char* pdst  = smem + 32768 + hf * 1024;         // + buf*4096 (ns==0)

    // pre-stage st 0 -> buf 0
    async16(gsrcA, gdstA);
    async16(gsrcB, gdstB);
    if (ns == 0) async16(psrc, pdst);
    __syncthreads();

    for (int st = 0; st < 16; st++) {
        const unsigned char* gcur = smem + (st & 1) * 16384 + hf * 4096;
        const unsigned char* pcur = smem + 32768 + (st & 1) * 4096 + hf * 1024;
        if (st < 15) {   // issue next st's DMA into the other buffers (no wait)
            int nb = (st + 1) & 1;
            int mo = (st + 1) << 6;          // 64 m-elements per st
            async16(gsrcA + mo, gdstA + nb * 16384);
            async16(gsrcB + mo, gdstB + nb * 16384);
            if (ns == 0) async16(psrc + (size_t)mo * 8, pdst + nb * 4096);
        }
#pragma unroll
        for (int t8 = 0; t8 < 2; t8++) {
            // phi A-frag: rows t8*32..+31 of this st window (contiguous 16B)
            s16x8 F = Fc;
            if (h == 0) F = *(const s16x8*)(pcur + ((t8 << 5) + c31) * 16);
            // G A-frags: logical slot 4*t8+2*pv+h, LDS slot = logical^(c31&7)
            int s0 = (t8 << 2) + h;
            int m7 = c31 & 7;
            s16x8 G1 = *(const s16x8*)(gcur + c31 * 128 + (((s0 + 0) ^ m7) << 4));
            s16x8 G2 = *(const s16x8*)(gcur + c31 * 128 + (((s0 + 2) ^ m7) << 4));

            f32x16 z = {};
            f32x16 S = __builtin_amdgcn_mfma_f32_32x32x16_bf16(F, BT, z, 0, 0, 0);

            float p0  = __builtin_amdgcn_exp2f(S[0]);
            float p1  = __builtin_amdgcn_exp2f(S[1]);
            float p2  = __builtin_amdgcn_exp2f(S[2]);
            float p3  = __builtin_amdgcn_exp2f(S[3]);
            float p4  = __builtin_amdgcn_exp2f(S[4]);
            float p5  = __builtin_amdgcn_exp2f(S[5]);
            float p6  = __builtin_amdgcn_exp2f(S[6]);
            float p7  = __builtin_amdgcn_exp2f(S[7]);
            float p8  = __builtin_amdgcn_exp2f(S[8]);
            float p9  = __builtin_amdgcn_exp2f(S[9]);
            float p10 = __builtin_amdgcn_exp2f(S[10]);
            float p11 = __builtin_amdgcn_exp2f(S[11]);
            float p12 = __builtin_amdgcn_exp2f(S[12]);
            float p13 = __builtin_amdgcn_exp2f(S[13]);
            float p14 = __builtin_amdgcn_exp2f(S[14]);
            float p15 = __builtin_amdgcn_exp2f(S[15]);

            // denominator on VALU: packed-f32 add tree (7 pk-adds)
            f32x2 u0 = (f32x2){p0, p1} + (f32x2){p2, p3};
            f32x2 u1 = (f32x2){p4, p5} + (f32x2){p6, p7};
            f32x2 u2 = (f32x2){p8, p9} + (f32x2){p10, p11};
            f32x2 u3 = (f32x2){p12, p13} + (f32x2){p14, p15};
            l2 += (u0 + u1) + (u2 + u3);

            // B-frags: direct in-lane packs (pi makes k-order = reg-order)
            uint4 ub1 = make_uint4(pk_tr(p0, p1), pk_tr(p2, p3),
                                   pk_tr(p4, p5), pk_tr(p6, p7));
            uint4 ub2 = make_uint4(pk_tr(p8, p9), pk_tr(p10, p11),
                                   pk_tr(p12, p13), pk_tr(p14, p15));
            s16x8 B1 = *(s16x8*)&ub1;
            s16x8 B2 = *(s16x8*)&ub2;

            acc = __builtin_amdgcn_mfma_f32_32x32x16_bf16(G1, B1, acc, 0, 0, 0);
            acc = __builtin_amdgcn_mfma_f32_32x32x16_bf16(G2, B2, acc, 0, 0, 0);
        }
        __syncthreads();   // single barrier/st; drains next-st DMA (vmcnt) too
    }

    // per-quarter denominator: combine h-halves (h=0: m%8<4, h=1: rest)
    float l = l2[0] + l2[1];
    l += __shfl_xor(l, 32);

    // cross-quarter combine: quarters 1..3 dump partials into retired LDS.
    // acc at 80B stride (bank-balanced), l as scalars.
    if (hf != 0) {
        int reg = (hf - 1) * 2 + ns;                       // 0..5
        *(f32x16*)(smem + reg * 5120 + lane * 80) = acc;   // [0, 30720)
        *(float*)(smem + 30720 + reg * 256 + lane * 4) = l;  // [30720, 32256)
    }
    __syncthreads();
    if (hf == 0) {
#pragma unroll
        for (int k = 0; k < 3; k++) {
            int reg = k * 2 + ns;
            acc += *(const f32x16*)(smem + reg * 5120 + lane * 80);
            l += *(const float*)(smem + 30720 + reg * 256 + lane * 4);
        }
        float linv = 1.0f / l;
        acc *= linv;

        // w_o A-frags: A[row=cc=16g4+nl][k=c=8q+j]
        s16x8 WO[4];
#pragma unroll
        for (int g4 = 0; g4 < 4; g4++) {
            const float4* wr = (const float4*)(w_o + (size_t)(g4 * 16 + nl) * 32 + q * 8);
            float4 a0 = wr[0], a1 = wr[1];
            WO[g4][0] = (short)f32_bf16(a0.x); WO[g4][1] = (short)f32_bf16(a0.y);
            WO[g4][2] = (short)f32_bf16(a0.z); WO[g4][3] = (short)f32_bf16(a0.w);
            WO[g4][4] = (short)f32_bf16(a1.x); WO[g4][5] = (short)f32_bf16(a1.y);
            WO[g4][6] = (short)f32_bf16(a1.z); WO[g4][7] = (short)f32_bf16(a1.w);
        }
        float gam = gamma[0];

        // O_s overlay [64 rows][80 B] at 34816 (no overlap with dump regions)
        unsigned char* O_s = smem + 34816;
        int nloc = ns * 32 + c31;
#pragma unroll
        for (int g2 = 0; g2 < 4; g2++) {
            uint2 ov;
            ov.x = pk_bf16(acc[4 * g2 + 0], acc[4 * g2 + 1]);
            ov.y = pk_bf16(acc[4 * g2 + 2], acc[4 * g2 + 3]);
            *(uint2*)(O_s + nloc * 80 + 16 * g2 + 8 * h) = ov;
        }
        int nloc0 = ns * 32 + nl;
        int nloc1 = nloc0 + 16;
        s16x8 OB0 = *(const s16x8*)(O_s + nloc0 * 80 + q * 16);  // wave-local rows
        s16x8 OB1 = *(const s16x8*)(O_s + nloc1 * 80 + q * 16);
#pragma unroll
        for (int g4 = 0; g4 < 4; g4++) {
            f32x4 e0 = (f32x4){0.f, 0.f, 0.f, 0.f};
            f32x4 e1 = (f32x4){0.f, 0.f, 0.f, 0.f};
            e0 = __builtin_amdgcn_mfma_f32_16x16x32_bf16(WO[g4], OB0, e0, 0, 0, 0);
            e1 = __builtin_amdgcn_mfma_f32_16x16x32_bf16(WO[g4], OB1, e1, 0, 0, 0);
#pragma unroll
            for (int r = 0; r < 4; r++) {
                int cc = g4 * 16 + q * 4 + r;
                size_t gi0 = (((size_t)(b * 64 + cc)) << 14) + nw + nl;
                out[gi0] = gam * e0[r] + x[gi0];
                size_t gi1 = gi0 + 16;
                out[gi1] = gam * e1[r] + x[gi1];
            }
        }
    }
}

extern "C" void kernel_launch(void* const* d_in, const int* in_sizes, int n_in,
                              void* d_out, int out_size, void* d_ws, size_t ws_size,
                              hipStream_t stream) {
    const float* x       = (const float*)d_in[0];
    const float* w_theta = (const float*)d_in[1];
    const float* w_phi   = (const float*)d_in[2];
    const float* w_g     = (const float*)d_in[3];
    const float* w_o     = (const float*)d_in[4];
    const float* gamma   = (const float*)d_in[5];
    float* out = (float*)d_out;

    __hip_bfloat16* thG = (__hip_bfloat16*)d_ws;        // 4*16384*8 = 1 MB
    __hip_bfloat16* phG = thG + 524288;                 // 4*4096*8  = 256 KB
    __hip_bfloat16* gG  = phG + 131072;                 // 4*32*4096 = 1 MB

    proj_kernel<<<512, 256, 0, stream>>>(x, w_theta, w_phi, w_g, thG, phG, gG);
    attn_kernel<<<1024, 512, 0, stream>>>(thG, phG, gG, w_o, gamma, x, out);
}

// Round 7
// 119.936 us; speedup vs baseline: 1.0685x; 1.0067x over previous
//
#include <hip/hip_runtime.h>
#include <hip/hip_bf16.h>

// SAGAN self-attention, MI355X gfx950. B=4, C=64, H=W=128, N=16384, M=4096.
// fp32 in/out. Round 17: remove AGPR round-trips. R16 showed occupancy 42%
// but flat duration; VALU cyc/tile = 274 vs ~190 necessary — the ~64-cyc gap
// = v_accvgpr moves forced by the VGPR cap (VGPR_Count 40 << ~75 live).
// Same m-quarter structure (grid 1024, 8 waves = 2 n-sub x 4 m-quarters,
// 16 sts x 64 m, 40960 B LDS) but launch_bounds(512,4): cap 128 VGPR, acc/S/
// zero-C stay in VGPRs, 2 blocks/CU (R14 proved that residency is enough).
// Inner tile = R13 verbatim (1 score MFMA + 2 PV MFMA per 32x32 tile,
// pi-permuted gG, VALU pk-add denominator).
// Layouts: 32x32x16 A[row=lane&31][k=8h+j], B[k=8h+j][col=lane&31]
// (h=lane>>5); C/D[row=(r&3)+8(r>>2)+4h][col=lane&31].

typedef __attribute__((ext_vector_type(16))) float f32x16;
typedef __attribute__((ext_vector_type(4))) float f32x4;
typedef __attribute__((ext_vector_type(2))) float f32x2;
typedef __attribute__((ext_vector_type(8))) short s16x8;

__device__ __forceinline__ unsigned short f32_bf16(float f) {
    unsigned int u = __float_as_uint(f);
    return (unsigned short)((u + 0x7fffu + ((u >> 16) & 1u)) >> 16);  // RNE
}
__device__ __forceinline__ unsigned int pk_bf16(float a, float b) {
    return (unsigned int)f32_bf16(a) | ((unsigned int)f32_bf16(b) << 16);
}
__device__ __forceinline__ unsigned int pk_rh(float a, float b) {   // round-half-up
    unsigned int au = __float_as_uint(a) + 0x8000u;
    unsigned int bu = __float_as_uint(b) + 0x8000u;
    return __builtin_amdgcn_perm(bu, au, 0x07060302u);
}
__device__ __forceinline__ unsigned int pk_tr(float a, float b) {   // truncate
    return __builtin_amdgcn_perm(__float_as_uint(b), __float_as_uint(a), 0x07060302u);
}
// async 16B/lane global->LDS DMA; lds dest = wave-uniform base + lane*16
__device__ __forceinline__ void async16(const void* g, void* l) {
    __builtin_amdgcn_global_load_lds(
        (const __attribute__((address_space(1))) unsigned int*)g,
        (__attribute__((address_space(3))) unsigned int*)l, 16, 0, 0);
}

// ---------------- proj: theta/phi/g 1x1 conv + 2x2 maxpool, MFMA ----------------
// (round 13 verbatim — passed; emits pi-permuted gG for the 32x32 PV)
__global__ __launch_bounds__(256) void proj_kernel(
    const float* __restrict__ x,
    const float* __restrict__ w_theta, const float* __restrict__ w_phi,
    const float* __restrict__ w_g,
    __hip_bfloat16* __restrict__ thG,   // [b][n][8]  (theta * log2e)
    __hip_bfloat16* __restrict__ phG,   // [b][m][8]
    __hip_bfloat16* __restrict__ gG)    // [b][32][4096], pi-permuted per 32-m chunk
{
    __shared__ __align__(16) unsigned short x_s[128 * 72];  // [pix][c], 144 B rows
    int tid = threadIdx.x;
    int bx = blockIdx.x;
    int b = bx >> 7, mh = (bx >> 1) & 63, ph = bx & 1;

    {   // phase 1: float4 loads (c-pair per thread), packed u32 LDS transpose
        int cp = tid >> 3, s = tid & 7;
        const float* xb = x + ((size_t)b << 20) + (size_t)(2 * mh) * 128 + 64 * ph;
        const float* p0r = xb + ((size_t)(2 * cp) << 14);
        const float* p1r = p0r + (1 << 14);
#pragma unroll
        for (int py = 0; py < 2; py++)
#pragma unroll
            for (int t = 0; t < 2; t++) {
                int pxl = 4 * s + 32 * t;
                float4 a = *(const float4*)(p0r + py * 128 + pxl);
                float4 c = *(const float4*)(p1r + py * 128 + pxl);
                int pix = py * 64 + pxl;
                *(unsigned int*)&x_s[(pix + 0) * 72 + 2 * cp] = pk_rh(a.x, c.x);
                *(unsigned int*)&x_s[(pix + 1) * 72 + 2 * cp] = pk_rh(a.y, c.y);
                *(unsigned int*)&x_s[(pix + 2) * 72 + 2 * cp] = pk_rh(a.z, c.z);
                *(unsigned int*)&x_s[(pix + 3) * 72 + 2 * cp] = pk_rh(a.w, c.w);
            }
    }

    int lane = tid & 63, w = tid >> 6;
    int q = lane >> 4, nl = lane & 15;

    s16x8 A[3][2];
#pragma unroll
    for (int CT = 0; CT < 3; CT++) {
        const float* wsrc;
        float scale = 1.0f;
        if (CT == 0) {
            if (nl < 8) { wsrc = w_theta + nl * 64; scale = 1.44269504f; }
            else        { wsrc = w_phi + (nl - 8) * 64; }
        } else if (CT == 1) wsrc = w_g + nl * 64;
        else                wsrc = w_g + (16 + nl) * 64;
#pragma unroll
        for (int ks = 0; ks < 2; ks++) {
            const float4* p4 = (const float4*)(wsrc + 32 * ks + 8 * q);
            float4 a0 = p4[0], a1 = p4[1];
            s16x8 f;
            f[0] = (short)f32_bf16(a0.x * scale); f[1] = (short)f32_bf16(a0.y * scale);
            f[2] = (short)f32_bf16(a0.z * scale); f[3] = (short)f32_bf16(a0.w * scale);
            f[4] = (short)f32_bf16(a1.x * scale); f[5] = (short)f32_bf16(a1.y * scale);
            f[6] = (short)f32_bf16(a1.z * scale); f[7] = (short)f32_bf16(a1.w * scale);
            A[CT][ks] = f;
        }
    }
    __syncthreads();

    f32x4 acc[3][2];
#pragma unroll
    for (int ti = 0; ti < 2; ti++) {
        int tile = w + 4 * ti;
        const unsigned short* rb = x_s + (16 * tile + nl) * 72;
        s16x8 B0 = *(const s16x8*)(rb + 8 * q);
        s16x8 B1 = *(const s16x8*)(rb + 32 + 8 * q);
#pragma unroll
        for (int CT = 0; CT < 3; CT++) {
            f32x4 d = (f32x4){0.f, 0.f, 0.f, 0.f};
            d = __builtin_amdgcn_mfma_f32_16x16x32_bf16(A[CT][0], B0, d, 0, 0, 0);
            d = __builtin_amdgcn_mfma_f32_16x16x32_bf16(A[CT][1], B1, d, 0, 0, 0);
            acc[CT][ti] = d;
        }
    }

    if (q < 2) {
        unsigned short* thb = (unsigned short*)thG + ((size_t)b << 14) * 8;
#pragma unroll
        for (int ti = 0; ti < 2; ti++) {
            int n = (2 * mh + ti) * 128 + 64 * ph + 16 * w + nl;
            uint2 tv;
            tv.x = pk_bf16(acc[0][ti][0], acc[0][ti][1]);
            tv.y = pk_bf16(acc[0][ti][2], acc[0][ti][3]);
            *(uint2*)(thb + (size_t)n * 8 + 4 * q) = tv;
        }
    }

    float pool[3][4];
#pragma unroll
    for (int CT = 0; CT < 3; CT++)
#pragma unroll
        for (int r = 0; r < 4; r++) {
            float a = fmaxf(acc[CT][0][r], acc[CT][1][r]);
            pool[CT][r] = fmaxf(a, __shfl_xor(a, 1));
        }

    int mm = 8 * w + (nl >> 1);
    int mbase = mh * 64 + ph * 32;
    if ((nl & 1) == 0) {
        if (q >= 2) {
            uint2 pv;
            pv.x = pk_bf16(pool[0][0], pool[0][1]);
            pv.y = pk_bf16(pool[0][2], pool[0][3]);
            *(uint2*)((unsigned short*)phG + ((size_t)(b * 4096 + mbase + mm)) * 8 + (q - 2) * 4) = pv;
        }
        // pi for 32x32 PV A-frags: i = 16*((mm>>4)&1) + 8*((mm>>2)&1) + 4*((mm>>3)&1) + (mm&3)
        int p = 16 * ((mm >> 4) & 1) + 8 * ((mm >> 2) & 1) + 4 * ((mm >> 3) & 1) + (mm & 3);
        int mstore = mbase + p;
#pragma unroll
        for (int CT = 1; CT < 3; CT++)
#pragma unroll
            for (int r = 0; r < 4; r++) {
                int cg = 16 * (CT - 1) + 4 * q + r;
                ((unsigned short*)gG)[((size_t)(b * 32 + cg) << 12) + mstore] =
                    f32_bf16(pool[CT][r]);
            }
    }
}

// ---------------- attn: m-quarter 8-wave, 32x32x16 score -> exp2 -> 2x PV ------
// Grid 1024 = b(4) x n-tile(256). Block 512 thr = 2 n-subtiles x 4 m-quarters.
// Each quarter: 16 sts x 64 m. LDS per quarter: g dbuf 2x4096 + phi dbuf 2x1024.
// Map: g [0,32768) = buf*16384 + hf*4096; phi [32768,40960) = buf*4096 + hf*1024.
__global__ __launch_bounds__(512, 4) void attn_kernel(
    const __hip_bfloat16* __restrict__ thG, const __hip_bfloat16* __restrict__ phG,
    const __hip_bfloat16* __restrict__ gG,
    const float* __restrict__ w_o, const float* __restrict__ gamma,
    const float* __restrict__ x, float* __restrict__ out)
{
    __shared__ __align__(64) unsigned char smem[40960];

    int tid = threadIdx.x, lane = tid & 63, w = tid >> 6;   // w: 0..7
    int ns = w & 1, hf = w >> 1;     // ns: n-subtile, hf: m-quarter (0..3)
    int q = lane >> 4, nl = lane & 15;
    int c31 = lane & 31, h = lane >> 5;
    int bx = blockIdx.x;
    int b  = bx >> 8;
    int n0 = (bx & 255) << 6;
    int nw = n0 + ns * 32;

    const unsigned short* thb = (const unsigned short*)thG + ((size_t)b << 14) * 8;
    const unsigned short* phb = (const unsigned short*)phG + ((size_t)b << 12) * 8;
    const unsigned short* ggb = (const unsigned short*)gG + ((size_t)b << 17);

    // theta B-frag (32x32x16): B[k=c=8h+j][col=n=c31]; h=1/j=0 = bias slot
    s16x8 BT = (s16x8){0, 0, 0, 0, 0, 0, 0, 0};
    if (h == 0) BT = *(const s16x8*)(thb + (size_t)(nw + c31) * 8);
    else        BT[0] = (short)0xC167;   // bf16(-14.4375)
    // phi A-frag const part: h=1/j=0 -> k=8 slot = 1.0
    s16x8 Fc = (s16x8){0, 0, 0, 0, 0, 0, 0, 0};
    if (h == 1) Fc[0] = (short)0x3F80;

    f32x16 acc = {};          // PV acc: [row=c=(r&3)+8(r>>2)+4h][col=n=c31]
    const f32x16 ZERO = {};   // hoisted MFMA C operand (stays in VGPRs)
    f32x2  l2 = (f32x2){0.f, 0.f};

    // staging: each quarter stages all 32 g-rows x its 64-m window per st.
    // Wave (hf,ns): 2 g-calls (rows 16ns..+7, 16ns+8..+15); ns==0 also phi.
    // 8 slots/row (16B = 8 m); LDS slot s of row r holds logical slot s^(r&7).
    int rA = 16 * ns + (lane >> 3);
    int rB = rA + 8;
    int wq = hf << 10;                   // quarter m-base (elements)
    const unsigned short* gsrcA = ggb + ((size_t)rA << 12) + wq
                                  + (((lane & 7) ^ (rA & 7)) << 3);
    const unsigned short* gsrcB = ggb + ((size_t)rB << 12) + wq
                                  + (((lane & 7) ^ (rB & 7)) << 3);
    const unsigned short* psrc  = phb + (size_t)(wq + lane) * 8;
    unsigned char* gdstA = smem + hf * 4096 + ns * 2048;     // + buf*16384
    unsigned char* gdstB = gdstA + 1024;
    unsigned char* pdst  = smem + 32768 + hf * 1024;         // + buf*4096 (ns==0)

    // pre-stage st 0 -> buf 0
    async16(gsrcA, gdstA);
    async16(gsrcB, gdstB);
    if (ns == 0) async16(psrc, pdst);
    __syncthreads();

    for (int st = 0; st < 16; st++) {
        const unsigned char* gcur = smem + (st & 1) * 16384 + hf * 4096;
        const unsigned char* pcur = smem + 32768 + (st & 1) * 4096 + hf * 1024;
        if (st < 15) {   // issue next st's DMA into the other buffers (no wait)
            int nb = (st + 1) & 1;
            int mo = (st + 1) << 6;          // 64 m-elements per st
            async16(gsrcA + mo, gdstA + nb * 16384);
            async16(gsrcB + mo, gdstB + nb * 16384);
            if (ns == 0) async16(psrc + (size_t)mo * 8, pdst + nb * 4096);
        }
#pragma unroll
        for (int t8 = 0; t8 < 2; t8++) {
            // phi A-frag: rows t8*32..+31 of this st window (contiguous 16B)
            s16x8 F = Fc;
            if (h == 0) F = *(const s16x8*)(pcur + ((t8 << 5) + c31) * 16);
            // G A-frags: logical slot 4*t8+2*pv+h, LDS slot = logical^(c31&7)
            int s0 = (t8 << 2) + h;
            int m7 = c31 & 7;
            s16x8 G1 = *(const s16x8*)(gcur + c31 * 128 + (((s0 + 0) ^ m7) << 4));
            s16x8 G2 = *(const s16x8*)(gcur + c31 * 128 + (((s0 + 2) ^ m7) << 4));

            f32x16 S = __builtin_amdgcn_mfma_f32_32x32x16_bf16(F, BT, ZERO, 0, 0, 0);

            float p0  = __builtin_amdgcn_exp2f(S[0]);
            float p1  = __builtin_amdgcn_exp2f(S[1]);
            float p2  = __builtin_amdgcn_exp2f(S[2]);
            float p3  = __builtin_amdgcn_exp2f(S[3]);
            float p4  = __builtin_amdgcn_exp2f(S[4]);
            float p5  = __builtin_amdgcn_exp2f(S[5]);
            float p6  = __builtin_amdgcn_exp2f(S[6]);
            float p7  = __builtin_amdgcn_exp2f(S[7]);
            float p8  = __builtin_amdgcn_exp2f(S[8]);
            float p9  = __builtin_amdgcn_exp2f(S[9]);
            float p10 = __builtin_amdgcn_exp2f(S[10]);
            float p11 = __builtin_amdgcn_exp2f(S[11]);
            float p12 = __builtin_amdgcn_exp2f(S[12]);
            float p13 = __builtin_amdgcn_exp2f(S[13]);
            float p14 = __builtin_amdgcn_exp2f(S[14]);
            float p15 = __builtin_amdgcn_exp2f(S[15]);

            // denominator on VALU: packed-f32 add tree (7 pk-adds)
            f32x2 u0 = (f32x2){p0, p1} + (f32x2){p2, p3};
            f32x2 u1 = (f32x2){p4, p5} + (f32x2){p6, p7};
            f32x2 u2 = (f32x2){p8, p9} + (f32x2){p10, p11};
            f32x2 u3 = (f32x2){p12, p13} + (f32x2){p14, p15};
            l2 += (u0 + u1) + (u2 + u3);

            // B-frags: direct in-lane packs (pi makes k-order = reg-order)
            uint4 ub1 = make_uint4(pk_tr(p0, p1), pk_tr(p2, p3),
                                   pk_tr(p4, p5), pk_tr(p6, p7));
            uint4 ub2 = make_uint4(pk_tr(p8, p9), pk_tr(p10, p11),
                                   pk_tr(p12, p13), pk_tr(p14, p15));
            s16x8 B1 = *(s16x8*)&ub1;
            s16x8 B2 = *(s16x8*)&ub2;

            acc = __builtin_amdgcn_mfma_f32_32x32x16_bf16(G1, B1, acc, 0, 0, 0);
            acc = __builtin_amdgcn_mfma_f32_32x32x16_bf16(G2, B2, acc, 0, 0, 0);
        }
        __syncthreads();   // single barrier/st; drains next-st DMA (vmcnt) too
    }

    // per-quarter denominator: combine h-halves (h=0: m%8<4, h=1: rest)
    float l = l2[0] + l2[1];
    l += __shfl_xor(l, 32);

    // cross-quarter combine: quarters 1..3 dump partials into retired LDS.
    // acc at 80B stride (bank-balanced), l as scalars.
    if (hf != 0) {
        int reg = (hf - 1) * 2 + ns;                       // 0..5
        *(f32x16*)(smem + reg * 5120 + lane * 80) = acc;   // [0, 30720)
        *(float*)(smem + 30720 + reg * 256 + lane * 4) = l;  // [30720, 32256)
    }
    __syncthreads();
    if (hf == 0) {
#pragma unroll
        for (int k = 0; k < 3; k++) {
            int reg = k * 2 + ns;
            acc += *(const f32x16*)(smem + reg * 5120 + lane * 80);
            l += *(const float*)(smem + 30720 + reg * 256 + lane * 4);
        }
        float linv = 1.0f / l;
        acc *= linv;

        // w_o A-frags: A[row=cc=16g4+nl][k=c=8q+j]
        s16x8 WO[4];
#pragma unroll
        for (int g4 = 0; g4 < 4; g4++) {
            const float4* wr = (const float4*)(w_o + (size_t)(g4 * 16 + nl) * 32 + q * 8);
            float4 a0 = wr[0], a1 = wr[1];
            WO[g4][0] = (short)f32_bf16(a0.x); WO[g4][1] = (short)f32_bf16(a0.y);
            WO[g4][2] = (short)f32_bf16(a0.z); WO[g4][3] = (short)f32_bf16(a0.w);
            WO[g4][4] = (short)f32_bf16(a1.x); WO[g4][5] = (short)f32_bf16(a1.y);
            WO[g4][6] = (short)f32_bf16(a1.z); WO[g4][7] = (short)f32_bf16(a1.w);
        }
        float gam = gamma[0];

        // O_s overlay [64 rows][80 B] at 34816 (no overlap with dump regions)
        unsigned char* O_s = smem + 34816;
        int nloc = ns * 32 + c31;
#pragma unroll
        for (int g2 = 0; g2 < 4; g2++) {
            uint2 ov;
            ov.x = pk_bf16(acc[4 * g2 + 0], acc[4 * g2 + 1]);
            ov.y = pk_bf16(acc[4 * g2 + 2], acc[4 * g2 + 3]);
            *(uint2*)(O_s + nloc * 80 + 16 * g2 + 8 * h) = ov;
        }
        int nloc0 = ns * 32 + nl;
        int nloc1 = nloc0 + 16;
        s16x8 OB0 = *(const s16x8*)(O_s + nloc0 * 80 + q * 16);  // wave-local rows
        s16x8 OB1 = *(const s16x8*)(O_s + nloc1 * 80 + q * 16);
#pragma unroll
        for (int g4 = 0; g4 < 4; g4++) {
            f32x4 e0 = (f32x4){0.f, 0.f, 0.f, 0.f};
            f32x4 e1 = (f32x4){0.f, 0.f, 0.f, 0.f};
            e0 = __builtin_amdgcn_mfma_f32_16x16x32_bf16(WO[g4], OB0, e0, 0, 0, 0);
            e1 = __builtin_amdgcn_mfma_f32_16x16x32_bf16(WO[g4], OB1, e1, 0, 0, 0);
#pragma unroll
            for (int r = 0; r < 4; r++) {
                int cc = g4 * 16 + q * 4 + r;
                size_t gi0 = (((size_t)(b * 64 + cc)) << 14) + nw + nl;
                out[gi0] = gam * e0[r] + x[gi0];
                size_t gi1 = gi0 + 16;
                out[gi1] = gam * e1[r] + x[gi1];
            }
        }
    }
}

extern "C" void kernel_launch(void* const* d_in, const int* in_sizes, int n_in,
                              void* d_out, int out_size, void* d_ws, size_t ws_size,
                              hipStream_t stream) {
    const float* x       = (const float*)d_in[0];
    const float* w_theta = (const float*)d_in[1];
    const float* w_phi   = (const float*)d_in[2];
    const float* w_g     = (const float*)d_in[3];
    const float* w_o     = (const float*)d_in[4];
    const float* gamma   = (const float*)d_in[5];
    float* out = (float*)d_out;

    __hip_bfloat16* thG = (__hip_bfloat16*)d_ws;        // 4*16384*8 = 1 MB
    __hip_bfloat16* phG = thG + 524288;                 // 4*4096*8  = 256 KB
    __hip_bfloat16* gG  = phG + 131072;                 // 4*32*4096 = 1 MB

    proj_kernel<<<512, 256, 0, stream>>>(x, w_theta, w_phi, w_g, thG, phG, gG);
    attn_kernel<<<1024, 512, 0, stream>>>(thG, phG, gG, w_o, gamma, x, out);
}